// Round 20
// baseline (568.042 us; speedup 1.0000x reference)
//
#include <hip/hip_runtime.h>
#include <hip/hip_fp16.h>

#define USER_N 100000
#define ITEM_N 50000
#define NN (USER_N + ITEM_N)
#define D 64
#define IMGD 1024
#define LDP 68
#define KSPLIT 4
#define KQ (IMGD / KSPLIT)

#define BUCKET_BITS 10
#define BROWS (1 << BUCKET_BITS)
#define NBUCK ((NN + BROWS - 1) >> BUCKET_BITS)   // 147
#define CHUNK 4096

typedef _Float16 v4h __attribute__((ext_vector_type(4)));
typedef _Float16 v8h __attribute__((ext_vector_type(8)));
typedef float v4f __attribute__((ext_vector_type(4)));

typedef __attribute__((address_space(1))) unsigned int GU32;
typedef __attribute__((address_space(3))) unsigned int LU32;

// ------ prep: cvt x0=[u16;i16] (+dup i16 into xB) | wt transpose ------------
// MUST run AFTER bucket_finalize2: x0 carve aliases recB (r19 NaN lesson).
__global__ __launch_bounds__(256) void prep_fused(
    const float* __restrict__ uE, const float* __restrict__ iE,
    __half* __restrict__ x0, __half* __restrict__ xBI,
    const float* __restrict__ W, _Float16* __restrict__ Wt16, int cvt_blocks)
{
    if (blockIdx.x < cvt_blocks) {
        const int i = blockIdx.x * 256 + threadIdx.x;
        const int n4u = USER_N * D / 4;
        const int n4 = NN * D / 4;
        if (i >= n4) return;
        const float4 v = (i < n4u) ? reinterpret_cast<const float4*>(uE)[i]
                                   : reinterpret_cast<const float4*>(iE)[i - n4u];
        union { uint2 u2; __half2 h[2]; } o;
        o.h[0] = __floats2half2_rn(v.x, v.y);
        o.h[1] = __floats2half2_rn(v.z, v.w);
        *reinterpret_cast<uint2*>(x0 + (size_t)i * 4) = o.u2;
        if (i >= n4u)
            *reinterpret_cast<uint2*>(xBI + (size_t)(i - n4u) * 4) = o.u2;
    } else {
        const int id = (blockIdx.x - cvt_blocks) * 256 + threadIdx.x;
        if (id >= D * IMGD) return;
        const int c = id >> 10;
        const int k = id & 1023;
        Wt16[id] = (_Float16)W[(size_t)k * D + c];
    }
}

// ---------- MEGA: gemm || g || e1U, roles 4:3:3 by blockIdx%10 --------------
__global__ __launch_bounds__(256) void gemm_g(
    const float* __restrict__ A, const _Float16* __restrict__ Wt16,
    float* __restrict__ P0, float* __restrict__ P123,
    const int* __restrict__ rpI, const int2* __restrict__ evI,
    const int* __restrict__ rpA, const int* __restrict__ spA,
    const int2* __restrict__ evA,
    const __half* __restrict__ src, float* __restrict__ out32,
    __half* __restrict__ e1p,
    int gemm_blocks, int g_blocks)
{
    __shared__ float As[32 * KQ];   // 32KB (gemm branch only)
    const int q = blockIdx.x / 10, r10 = blockIdx.x % 10;
    union cvt4 { uint4 u; __half2 h[4]; };
    if (r10 < 4) {
        const int gb = q * 4 + r10;
        if (gb >= gemm_blocks) return;
        const int t = threadIdx.x;
        const int w = t >> 6;
        const int lane = t & 63;
        const int l16 = lane & 15;
        const int g = lane >> 4;
        const int tile = gb >> 2;
        const int ks = gb & 3;
        const int row0 = tile * 32;
        const int kbase = ks * KQ;

#pragma unroll
        for (int i = 0; i < 8; i++) {
            const int r = w * 8 + i;
            const int grow = row0 + r;
            const int garow = grow < ITEM_N ? grow : ITEM_N - 1;
            const int xm = (r & 7) << 4;
            const char* srcp = reinterpret_cast<const char*>(
                A + (size_t)garow * IMGD + kbase) + ((lane * 16) ^ xm);
            __builtin_amdgcn_global_load_lds(
                (GU32*)srcp, (LU32*)&As[r * KQ], 16, 0, 0);
        }
        asm volatile("s_waitcnt vmcnt(0)" ::: "memory");
        __syncthreads();

        const int wr = (w >> 1) * 16;
        const int wc = (w & 1) * 32;
        const int rr = wr + l16;
        const char* rbase = reinterpret_cast<const char*>(&As[rr * KQ]);
        const int xm = (rr & 7) << 4;

        v4f acc[2] = {};
        const _Float16* wb = Wt16 + (size_t)l16 * IMGD + kbase + g * 4;

        for (int c = 0; c < KQ; c += 64) {
            const int cb = c * 4;
            const float4 f0 = *reinterpret_cast<const float4*>(rbase + ((cb + g * 16) ^ xm));
            const float4 f1 = *reinterpret_cast<const float4*>(rbase + ((cb + 64 + g * 16) ^ xm));
            const float4 f2 = *reinterpret_cast<const float4*>(rbase + ((cb + 128 + g * 16) ^ xm));
            const float4 f3 = *reinterpret_cast<const float4*>(rbase + ((cb + 192 + g * 16) ^ xm));
            union { v8h v; v4h h[2]; } af0, af1;
            {
                v4h h;
                h[0] = (_Float16)f0.x; h[1] = (_Float16)f0.y;
                h[2] = (_Float16)f0.z; h[3] = (_Float16)f0.w;
                af0.h[0] = h;
                h[0] = (_Float16)f1.x; h[1] = (_Float16)f1.y;
                h[2] = (_Float16)f1.z; h[3] = (_Float16)f1.w;
                af0.h[1] = h;
                h[0] = (_Float16)f2.x; h[1] = (_Float16)f2.y;
                h[2] = (_Float16)f2.z; h[3] = (_Float16)f2.w;
                af1.h[0] = h;
                h[0] = (_Float16)f3.x; h[1] = (_Float16)f3.y;
                h[2] = (_Float16)f3.z; h[3] = (_Float16)f3.w;
                af1.h[1] = h;
            }
#pragma unroll
            for (int n = 0; n < 2; n++) {
                const _Float16* wp = wb + (size_t)(wc + n * 16) * IMGD + c;
                union { v8h v; v4h h[2]; } bf;
                bf.h[0] = *reinterpret_cast<const v4h*>(wp);
                bf.h[1] = *reinterpret_cast<const v4h*>(wp + 16);
                acc[n] = __builtin_amdgcn_mfma_f32_16x16x32_f16(af0.v, bf.v, acc[n], 0, 0, 0);
                bf.h[0] = *reinterpret_cast<const v4h*>(wp + 32);
                bf.h[1] = *reinterpret_cast<const v4h*>(wp + 48);
                acc[n] = __builtin_amdgcn_mfma_f32_16x16x32_f16(af1.v, bf.v, acc[n], 0, 0, 0);
            }
        }
        float* Cp = (ks == 0) ? P0 : P123 + (size_t)(ks - 1) * ITEM_N * D;
#pragma unroll
        for (int n = 0; n < 2; n++) {
            const int col = wc + n * 16 + l16;
#pragma unroll
            for (int r = 0; r < 4; r++) {
                const int grow = row0 + wr + g * 4 + r;
                if (grow < ITEM_N)
                    Cp[(size_t)grow * D + col] = acc[n][r];
            }
        }
    } else if (r10 < 7) {
        // ---- g = img_adj @ x0 (full range) ----
        const int sb = q * 3 + (r10 - 4);
        if (sb >= g_blocks) return;
        const int wid = (sb * 256 + threadIdx.x) >> 6;
        const int lane = threadIdx.x & 63;
        const int sub = lane >> 3;
        const int l8 = lane & 7;
        const int rowbase = wid * 8;
        if (rowbase >= NN) return;
        const int row = rowbase + sub;

        int v = 0;
        if (lane <= 8 && rowbase + lane <= NN) v = rpI[rowbase + lane];
        const int s = __shfl(v, sub, 64);
        const int e = __shfl(v, sub + 1, 64);

        const __half* srcl = src + l8 * 8;
        float acc[8] = {};

        int i = s;
        for (; i + 3 < e; i += 4) {
            const int2 E0 = evI[i], E1 = evI[i + 1], E2 = evI[i + 2], E3 = evI[i + 3];
            cvt4 g0, g1, g2, g3;
            g0.u = *reinterpret_cast<const uint4*>(srcl + (size_t)E0.x * D);
            g1.u = *reinterpret_cast<const uint4*>(srcl + (size_t)E1.x * D);
            g2.u = *reinterpret_cast<const uint4*>(srcl + (size_t)E2.x * D);
            g3.u = *reinterpret_cast<const uint4*>(srcl + (size_t)E3.x * D);
#pragma unroll
            for (int k = 0; k < 4; k++) {
                const cvt4& g = k == 0 ? g0 : k == 1 ? g1 : k == 2 ? g2 : g3;
                const float w = __int_as_float(k == 0 ? E0.y : k == 1 ? E1.y
                                               : k == 2 ? E2.y : E3.y);
#pragma unroll
                for (int j = 0; j < 4; j++) {
                    const float2 f = __half22float2(g.h[j]);
                    acc[2 * j]     += w * f.x;
                    acc[2 * j + 1] += w * f.y;
                }
            }
        }
        for (; i < e; i++) {
            const int2 E0 = evI[i];
            cvt4 g;
            g.u = *reinterpret_cast<const uint4*>(srcl + (size_t)E0.x * D);
            const float w = __int_as_float(E0.y);
#pragma unroll
            for (int j = 0; j < 4; j++) {
                const float2 f = __half22float2(g.h[j]);
                acc[2 * j]     += w * f.x;
                acc[2 * j + 1] += w * f.y;
            }
        }

        if (row >= NN) return;
        const size_t idx = (size_t)row * D + l8 * 8;
#pragma unroll
        for (int h = 0; h < 2; h++) {
            float4 o;
            o.x = acc[4 * h]; o.y = acc[4 * h + 1];
            o.z = acc[4 * h + 2]; o.w = acc[4 * h + 3];
            *reinterpret_cast<float4*>(&out32[idx + h * 4]) = o;
        }
    } else {
        // ---- e1U = adj user-edges [rp, sp) @ u16 -> fp16 partial (e1p) ----
        const int sb = q * 3 + (r10 - 7);
        if (sb >= g_blocks) return;
        const int wid = (sb * 256 + threadIdx.x) >> 6;
        const int lane = threadIdx.x & 63;
        const int sub = lane >> 3;
        const int l8 = lane & 7;
        const int rowbase = wid * 8;
        if (rowbase >= NN) return;
        const int row = rowbase + sub;

        int v = 0, u = 0;
        if (lane <= 8 && rowbase + lane <= NN) v = rpA[rowbase + lane];
        if (lane < 8 && rowbase + lane < NN) u = spA[rowbase + lane];
        const int s = __shfl(v, sub, 64);
        const int e = __shfl(u, sub, 64);   // [rp, sp) = user edges

        const __half* srcl = src + l8 * 8;
        float acc[8] = {};

        int i = s;
        for (; i + 3 < e; i += 4) {
            const int2 E0 = evA[i], E1 = evA[i + 1], E2 = evA[i + 2], E3 = evA[i + 3];
            cvt4 g0, g1, g2, g3;
            g0.u = *reinterpret_cast<const uint4*>(srcl + (size_t)E0.x * D);
            g1.u = *reinterpret_cast<const uint4*>(srcl + (size_t)E1.x * D);
            g2.u = *reinterpret_cast<const uint4*>(srcl + (size_t)E2.x * D);
            g3.u = *reinterpret_cast<const uint4*>(srcl + (size_t)E3.x * D);
#pragma unroll
            for (int k = 0; k < 4; k++) {
                const cvt4& g = k == 0 ? g0 : k == 1 ? g1 : k == 2 ? g2 : g3;
                const float w = __int_as_float(k == 0 ? E0.y : k == 1 ? E1.y
                                               : k == 2 ? E2.y : E3.y);
#pragma unroll
                for (int j = 0; j < 4; j++) {
                    const float2 f = __half22float2(g.h[j]);
                    acc[2 * j]     += w * f.x;
                    acc[2 * j + 1] += w * f.y;
                }
            }
        }
        for (; i < e; i++) {
            const int2 E0 = evA[i];
            cvt4 g;
            g.u = *reinterpret_cast<const uint4*>(srcl + (size_t)E0.x * D);
            const float w = __int_as_float(E0.y);
#pragma unroll
            for (int j = 0; j < 4; j++) {
                const float2 f = __half22float2(g.h[j]);
                acc[2 * j]     += w * f.x;
                acc[2 * j + 1] += w * f.y;
            }
        }

        if (row >= NN) return;
        const size_t idx = (size_t)row * D + l8 * 8;
        cvt4 o16;
#pragma unroll
        for (int j = 0; j < 4; j++)
            o16.h[j] = __floats2half2_rn(acc[2 * j], acc[2 * j + 1]);
        *reinterpret_cast<uint4*>(&e1p[idx]) = o16.u;
    }
}

// ---- e1 fix-up: item edges [sp, rp+1) @ featsN16 + fp16 partial ------------
__global__ __launch_bounds__(256) void spmm_fix(
    const int* __restrict__ rp, const int* __restrict__ sp,
    const int2* __restrict__ ev, const __half* __restrict__ src,
    const __half* __restrict__ partial,
    float* __restrict__ out32, __half* __restrict__ out16, int limit16)
{
    const int wid = (blockIdx.x * 256 + threadIdx.x) >> 6;
    const int lane = threadIdx.x & 63;
    const int sub = lane >> 3;
    const int l8 = lane & 7;
    const int rowbase = wid * 8;
    if (rowbase >= NN) return;
    const int row = rowbase + sub;

    int v = 0, u = 0;
    if (lane <= 8 && rowbase + lane <= NN) v = rp[rowbase + lane];
    if (lane < 8 && rowbase + lane < NN) u = sp[rowbase + lane];
    const int s = __shfl(u, sub, 64);       // sp[row]
    const int e = __shfl(v, sub + 1, 64);   // rp[row+1]

    const __half* srcl = src + l8 * 8;
    float acc[8];
    union cvt4 { uint4 u; __half2 h[4]; };
    {
        const size_t idx0 = (size_t)((row < NN) ? row : 0) * D + l8 * 8;
        cvt4 p;
        p.u = *reinterpret_cast<const uint4*>(&partial[idx0]);
#pragma unroll
        for (int j = 0; j < 4; j++) {
            const float2 f = __half22float2(p.h[j]);
            acc[2 * j] = f.x;
            acc[2 * j + 1] = f.y;
        }
    }

    int i = s;
    for (; i + 3 < e; i += 4) {
        const int2 E0 = ev[i], E1 = ev[i + 1], E2 = ev[i + 2], E3 = ev[i + 3];
        cvt4 g0, g1, g2, g3;
        g0.u = *reinterpret_cast<const uint4*>(srcl + (size_t)E0.x * D);
        g1.u = *reinterpret_cast<const uint4*>(srcl + (size_t)E1.x * D);
        g2.u = *reinterpret_cast<const uint4*>(srcl + (size_t)E2.x * D);
        g3.u = *reinterpret_cast<const uint4*>(srcl + (size_t)E3.x * D);
#pragma unroll
        for (int k = 0; k < 4; k++) {
            const cvt4& g = k == 0 ? g0 : k == 1 ? g1 : k == 2 ? g2 : g3;
            const float w = __int_as_float(k == 0 ? E0.y : k == 1 ? E1.y
                                           : k == 2 ? E2.y : E3.y);
#pragma unroll
            for (int j = 0; j < 4; j++) {
                const float2 f = __half22float2(g.h[j]);
                acc[2 * j]     += w * f.x;
                acc[2 * j + 1] += w * f.y;
            }
        }
    }
    for (; i < e; i++) {
        const int2 E0 = ev[i];
        cvt4 g;
        g.u = *reinterpret_cast<const uint4*>(srcl + (size_t)E0.x * D);
        const float w = __int_as_float(E0.y);
#pragma unroll
        for (int j = 0; j < 4; j++) {
            const float2 f = __half22float2(g.h[j]);
            acc[2 * j]     += w * f.x;
            acc[2 * j + 1] += w * f.y;
        }
    }

    if (row >= NN) return;
    const size_t idx = (size_t)row * D + l8 * 8;
#pragma unroll
    for (int h = 0; h < 2; h++) {
        float4 o;
        o.x = acc[4 * h]; o.y = acc[4 * h + 1];
        o.z = acc[4 * h + 2]; o.w = acc[4 * h + 3];
        *reinterpret_cast<float4*>(&out32[idx + h * 4]) = o;
    }
    if (row < limit16) {
        cvt4 o16;
#pragma unroll
        for (int j = 0; j < 4; j++)
            o16.h[j] = __floats2half2_rn(acc[2 * j], acc[2 * j + 1]);
        *reinterpret_cast<uint4*>(&out16[idx]) = o16.u;
    }
}

// ------------- fp32 GEMM (fallback path) ------------------------------------
__global__ __launch_bounds__(256) void gemm_feats32(
    const float* __restrict__ A, const float* __restrict__ W,
    const float* __restrict__ b, float* __restrict__ C)
{
    __shared__ float As[32][LDP];
    __shared__ float Ws[64][LDP];
    const int row0 = blockIdx.x * 32;
    const int t = threadIdx.x;
    const int tx = t & 15, ty = t >> 4;
    float acc[2][4] = {};

    const int lr = t >> 4;
    const int lk = (t & 15) * 4;

    for (int k0 = 0; k0 < IMGD; k0 += 64) {
#pragma unroll
        for (int i = 0; i < 2; i++) {
            const int r = lr + i * 16;
            const int grow = row0 + r;
            float4 v = make_float4(0.f, 0.f, 0.f, 0.f);
            if (grow < ITEM_N)
                v = *reinterpret_cast<const float4*>(&A[(size_t)grow * IMGD + k0 + lk]);
            *reinterpret_cast<float4*>(&As[r][lk]) = v;
        }
#pragma unroll
        for (int i = 0; i < 4; i++) {
            const int kr = lr + i * 16;
            float4 v = *reinterpret_cast<const float4*>(&W[(size_t)(k0 + kr) * D + lk]);
            *reinterpret_cast<float4*>(&Ws[kr][lk]) = v;
        }
        __syncthreads();
#pragma unroll
        for (int kb = 0; kb < 16; kb++) {
            float a_[2][4], w_[4][4];
#pragma unroll
            for (int i = 0; i < 2; i++) {
                const float4 v = *reinterpret_cast<const float4*>(&As[ty * 2 + i][kb * 4]);
                a_[i][0] = v.x; a_[i][1] = v.y; a_[i][2] = v.z; a_[i][3] = v.w;
            }
#pragma unroll
            for (int j = 0; j < 4; j++) {
                const float4 v = *reinterpret_cast<const float4*>(&Ws[kb * 4 + j][tx * 4]);
                w_[j][0] = v.x; w_[j][1] = v.y; w_[j][2] = v.z; w_[j][3] = v.w;
            }
#pragma unroll
            for (int j = 0; j < 4; j++)
#pragma unroll
                for (int i = 0; i < 2; i++)
#pragma unroll
                    for (int c = 0; c < 4; c++)
                        acc[i][c] += a_[i][j] * w_[j][c];
        }
        __syncthreads();
    }
    const float4 bias = *reinterpret_cast<const float4*>(&b[tx * 4]);
#pragma unroll
    for (int i = 0; i < 2; i++) {
        const int grow = row0 + ty * 2 + i;
        if (grow < ITEM_N) {
            float4 v;
            v.x = acc[i][0] + bias.x;
            v.y = acc[i][1] + bias.y;
            v.z = acc[i][2] + bias.z;
            v.w = acc[i][3] + bias.w;
            *reinterpret_cast<float4*>(&C[(size_t)grow * D + tx * 4]) = v;
        }
    }
}

// ---- Row L2 norm of (P0+P1+P2+P3+bias) -> fp16 (one wave per row) ----------
__global__ __launch_bounds__(256) void rownorm_h4(
    const float* __restrict__ P0, const float* __restrict__ P123,
    const float* __restrict__ b, __half* __restrict__ Y, int nrows)
{
    const int gid = blockIdx.x * blockDim.x + threadIdx.x;
    const int row = gid >> 6;
    const int lane = threadIdx.x & 63;
    if (row >= nrows) return;
    const size_t idx = (size_t)row * D + lane;
    const size_t N1 = (size_t)ITEM_N * D;
    float v = P0[idx] + P123[idx] + P123[idx + N1] + P123[idx + 2 * N1] + b[lane];
    float s = v * v;
#pragma unroll
    for (int o = 32; o > 0; o >>= 1) s += __shfl_xor(s, o, 64);
    const float scale = 1.0f / fmaxf(sqrtf(s), 1e-12f);
    Y[idx] = __float2half(v * scale);
}

__global__ __launch_bounds__(256) void rownorm(float* __restrict__ X, int nrows)
{
    const int gid = blockIdx.x * blockDim.x + threadIdx.x;
    const int row = gid >> 6;
    const int lane = threadIdx.x & 63;
    if (row >= nrows) return;
    float v = X[(size_t)row * D + lane];
    float s = v * v;
#pragma unroll
    for (int o = 32; o > 0; o >>= 1) s += __shfl_xor(s, o, 64);
    const float scale = 1.0f / fmaxf(sqrtf(s), 1e-12f);
    X[(size_t)row * D + lane] = v * scale;
}

// ============== CSR build (merged adj+img stages) ===========================
__global__ __launch_bounds__(256) void bucket_count2(
    const int* __restrict__ rows_a, int nnz_a, int nb_a, int* __restrict__ histT_a,
    const int* __restrict__ rows_b, int nnz_b, int nb_b, int* __restrict__ histT_b)
{
    const bool isA = (int)blockIdx.x < nb_a;
    const int bid = isA ? blockIdx.x : blockIdx.x - nb_a;
    const int* rows = isA ? rows_a : rows_b;
    const int nnz = isA ? nnz_a : nnz_b;
    const int nb = isA ? nb_a : nb_b;
    int* histT = isA ? histT_a : histT_b;

    __shared__ int cnt[NBUCK];
    for (int i = threadIdx.x; i < NBUCK; i += 256) cnt[i] = 0;
    __syncthreads();
    const int e0 = bid * CHUNK;
    const int e1 = min(e0 + CHUNK, nnz);
    for (int e = e0 + threadIdx.x; e < e1; e += 256)
        atomicAdd(&cnt[rows[e] >> BUCKET_BITS], 1);
    __syncthreads();
    for (int b = threadIdx.x; b < NBUCK; b += 256)
        histT[b * nb + bid] = cnt[b];
}

__global__ __launch_bounds__(1024) void scanA2(
    int* __restrict__ histTA, int* __restrict__ bsumsA, int nA, int nsbA,
    int* __restrict__ histTB, int* __restrict__ bsumsB, int nB)
{
    const bool isA = (int)blockIdx.x < nsbA;
    int* cnt = isA ? histTA : histTB;
    int* bsums = isA ? bsumsA : bsumsB;
    const int n = isA ? nA : nB;
    const int bid = isA ? blockIdx.x : blockIdx.x - nsbA;

    const int t = threadIdx.x;
    const int gid = bid * 1024 + t;
    const int lane = t & 63, wid = t >> 6;
    int v = (gid < n) ? cnt[gid] : 0;
    int x = v;
#pragma unroll
    for (int o = 1; o < 64; o <<= 1) {
        int y = __shfl_up(x, o, 64);
        if (lane >= o) x += y;
    }
    __shared__ int ws[16];
    __shared__ int wo[16];
    if (lane == 63) ws[wid] = x;
    __syncthreads();
    if (t < 16) {
        int s = ws[t];
        int xx = s;
#pragma unroll
        for (int o = 1; o < 16; o <<= 1) {
            int y = __shfl_up(xx, o, 16);
            if (t >= o) xx += y;
        }
        wo[t] = xx - s;
        if (t == 15) bsums[bid] = xx;
    }
    __syncthreads();
    if (gid < n) cnt[gid] = x - v + wo[wid];
}

__global__ __launch_bounds__(1024) void scanB2(
    int* __restrict__ bsA, int nbA, int* __restrict__ bsB, int nbB)
{
    int* bs = blockIdx.x == 0 ? bsA : bsB;
    const int nb = blockIdx.x == 0 ? nbA : nbB;
    const int t = threadIdx.x;
    const int lane = t & 63, wid = t >> 6;
    int v = (t < nb) ? bs[t] : 0;
    int x = v;
#pragma unroll
    for (int o = 1; o < 64; o <<= 1) {
        int y = __shfl_up(x, o, 64);
        if (lane >= o) x += y;
    }
    __shared__ int ws[16];
    __shared__ int wo[16];
    if (lane == 63) ws[wid] = x;
    __syncthreads();
    if (t < 16) {
        int s = ws[t];
        int xx = s;
#pragma unroll
        for (int o = 1; o < 16; o <<= 1) {
            int y = __shfl_up(xx, o, 16);
            if (t >= o) xx += y;
        }
        wo[t] = xx - s;
    }
    __syncthreads();
    if (t < nb) bs[t] = x - v + wo[wid];
}

__global__ __launch_bounds__(256) void scan_apply2(
    int* __restrict__ histTA, const int* __restrict__ bsA, int nA,
    int* __restrict__ histTB, const int* __restrict__ bsB, int nB)
{
    const int gid = blockIdx.x * blockDim.x + threadIdx.x;
    if (gid < nA) histTA[gid] += bsA[gid >> 10];
    else if (gid - nA < nB) histTB[gid - nA] += bsB[(gid - nA) >> 10];
}

__global__ __launch_bounds__(256) void bucket_place2(
    const int* __restrict__ rows_a, const int* __restrict__ cols_a,
    const float* __restrict__ vals_a, int nnz_a, int nb_a,
    const int* __restrict__ offsT_a, uint2* __restrict__ rec_a,
    const int* __restrict__ rows_b, const int* __restrict__ cols_b,
    const float* __restrict__ vals_b, int nnz_b, int nb_b,
    const int* __restrict__ offsT_b, uint2* __restrict__ rec_b)
{
    const bool isA = (int)blockIdx.x < nb_a;
    const int bid = isA ? blockIdx.x : blockIdx.x - nb_a;
    const int* rows = isA ? rows_a : rows_b;
    const int* cols = isA ? cols_a : cols_b;
    const float* vals = isA ? vals_a : vals_b;
    const int nnz = isA ? nnz_a : nnz_b;
    const int nb = isA ? nb_a : nb_b;
    const int* offsT = isA ? offsT_a : offsT_b;
    uint2* rec = isA ? rec_a : rec_b;

    __shared__ int cur[NBUCK];
    for (int b = threadIdx.x; b < NBUCK; b += 256)
        cur[b] = offsT[b * nb + bid];
    __syncthreads();
    const int e0 = bid * CHUNK;
    const int e1 = min(e0 + CHUNK, nnz);
    for (int e = e0 + threadIdx.x; e < e1; e += 256) {
        const int r = rows[e];
        const int b = r >> BUCKET_BITS;
        const int pos = atomicAdd(&cur[b], 1);
        rec[pos] = make_uint2(((unsigned)cols[e] << BUCKET_BITS) |
                                  (unsigned)(r & (BROWS - 1)),
                              __float_as_uint(vals[e]));
    }
}

// finalize with user/item partition per row (user edges first), emits sp
__global__ __launch_bounds__(1024) void bucket_finalize2(
    const uint2* __restrict__ rec_a, int nnz_a, int nb_a,
    const int* __restrict__ offsT_a, int* __restrict__ rp_a, int2* __restrict__ ev_a,
    int* __restrict__ sp_a,
    const uint2* __restrict__ rec_b, int nnz_b, int nb_b,
    const int* __restrict__ offsT_b, int* __restrict__ rp_b, int2* __restrict__ ev_b)
{
    const bool isA = (int)blockIdx.x < NBUCK;
    const int b = isA ? blockIdx.x : blockIdx.x - NBUCK;
    const uint2* rec = isA ? rec_a : rec_b;
    const int nnz = isA ? nnz_a : nnz_b;
    const int nb = isA ? nb_a : nb_b;
    const int* offsT = isA ? offsT_a : offsT_b;
    int* rp = isA ? rp_a : rp_b;
    int2* ev = isA ? ev_a : ev_b;

    const int t = threadIdx.x;
    const int rlo = b << BUCKET_BITS;
    const int segs = offsT[b * nb];
    const int sege = (b + 1 < NBUCK) ? offsT[(b + 1) * nb] : nnz;

    __shared__ int cnt[BROWS];
    __shared__ int cntU[BROWS];
    __shared__ int curU[BROWS];
    __shared__ int curI[BROWS];
    cnt[t] = 0;
    cntU[t] = 0;
    __syncthreads();
    for (int i = segs + t; i < sege; i += 1024) {
        const unsigned x = rec[i].x;
        const int rl = (int)(x & (BROWS - 1));
        atomicAdd(&cnt[rl], 1);
        if ((int)(x >> BUCKET_BITS) < USER_N) atomicAdd(&cntU[rl], 1);
    }
    __syncthreads();

    const int lane = t & 63, wid = t >> 6;
    const int v = cnt[t];
    int x = v;
#pragma unroll
    for (int o = 1; o < 64; o <<= 1) {
        int y = __shfl_up(x, o, 64);
        if (lane >= o) x += y;
    }
    __shared__ int wsum[16];
    __shared__ int woff[16];
    if (lane == 63) wsum[wid] = x;
    __syncthreads();
    if (t < 16) {
        int s = wsum[t];
        int xx = s;
#pragma unroll
        for (int o = 1; o < 16; o <<= 1) {
            int y = __shfl_up(xx, o, 16);
            if (t >= o) xx += y;
        }
        woff[t] = xx - s;
    }
    __syncthreads();
    const int start = segs + (x - v + woff[wid]);

    if (rlo + t < NN) {
        rp[rlo + t] = start;
        if (isA) sp_a[rlo + t] = start + cntU[t];
    }
    if (b == NBUCK - 1 && t == 0) rp[NN] = nnz;
    curU[t] = start;
    curI[t] = start + cntU[t];
    __syncthreads();

    for (int i = segs + t; i < sege; i += 1024) {
        const uint2 R = rec[i];
        const int rl = (int)(R.x & (BROWS - 1));
        const int c = (int)(R.x >> BUCKET_BITS);
        const int pos = atomicAdd((c < USER_N) ? &curU[rl] : &curI[rl], 1);
        ev[pos] = make_int2(c, (int)R.y);
    }
}

// ------- CSR SPMM v5: 8 rows per wave (8 lanes x 16B per row) ---------------
__global__ __launch_bounds__(256) void spmm_h8(
    const int* __restrict__ rp, const int2* __restrict__ ev,
    const __half* __restrict__ src,
    float* __restrict__ out32, __half* __restrict__ out16, int limit16,
    const float* __restrict__ add1, const float* __restrict__ add2)
{
    const int wid = (blockIdx.x * 256 + threadIdx.x) >> 6;
    const int lane = threadIdx.x & 63;
    const int sub = lane >> 3;
    const int l8 = lane & 7;
    const int rowbase = wid * 8;
    if (rowbase >= NN) return;
    const int row = rowbase + sub;

    int v = 0;
    if (lane <= 8 && rowbase + lane <= NN) v = rp[rowbase + lane];
    const int s = __shfl(v, sub, 64);
    const int e = __shfl(v, sub + 1, 64);

    const __half* srcl = src + l8 * 8;
    float acc[8] = {};

    union cvt4 { uint4 u; __half2 h[4]; };
    int i = s;
    for (; i + 3 < e; i += 4) {
        const int2 E0 = ev[i], E1 = ev[i + 1], E2 = ev[i + 2], E3 = ev[i + 3];
        cvt4 g0, g1, g2, g3;
        g0.u = *reinterpret_cast<const uint4*>(srcl + (size_t)E0.x * D);
        g1.u = *reinterpret_cast<const uint4*>(srcl + (size_t)E1.x * D);
        g2.u = *reinterpret_cast<const uint4*>(srcl + (size_t)E2.x * D);
        g3.u = *reinterpret_cast<const uint4*>(srcl + (size_t)E3.x * D);
#pragma unroll
        for (int k = 0; k < 4; k++) {
            const cvt4& g = k == 0 ? g0 : k == 1 ? g1 : k == 2 ? g2 : g3;
            const float w = __int_as_float(k == 0 ? E0.y : k == 1 ? E1.y
                                           : k == 2 ? E2.y : E3.y);
#pragma unroll
            for (int j = 0; j < 4; j++) {
                const float2 f = __half22float2(g.h[j]);
                acc[2 * j]     += w * f.x;
                acc[2 * j + 1] += w * f.y;
            }
        }
    }
    for (; i < e; i++) {
        const int2 E0 = ev[i];
        cvt4 g;
        g.u = *reinterpret_cast<const uint4*>(srcl + (size_t)E0.x * D);
        const float w = __int_as_float(E0.y);
#pragma unroll
        for (int j = 0; j < 4; j++) {
            const float2 f = __half22float2(g.h[j]);
            acc[2 * j]     += w * f.x;
            acc[2 * j + 1] += w * f.y;
        }
    }

    if (row >= NN) return;
    const size_t idx = (size_t)row * D + l8 * 8;
#pragma unroll
    for (int h = 0; h < 2; h++) {
        if (add1) {
            const float4 a = *reinterpret_cast<const float4*>(&add1[idx + h * 4]);
            acc[4 * h] += a.x; acc[4 * h + 1] += a.y;
            acc[4 * h + 2] += a.z; acc[4 * h + 3] += a.w;
        }
        if (add2) {
            const float4 a = *reinterpret_cast<const float4*>(&add2[idx + h * 4]);
            acc[4 * h] += a.x; acc[4 * h + 1] += a.y;
            acc[4 * h + 2] += a.z; acc[4 * h + 3] += a.w;
        }
        float4 o;
        o.x = acc[4 * h]; o.y = acc[4 * h + 1];
        o.z = acc[4 * h + 2]; o.w = acc[4 * h + 3];
        *reinterpret_cast<float4*>(&out32[idx + h * 4]) = o;
    }
    if (row < limit16) {
        cvt4 o16;
#pragma unroll
        for (int j = 0; j < 4; j++)
            o16.h[j] = __floats2half2_rn(acc[2 * j], acc[2 * j + 1]);
        *reinterpret_cast<uint4*>(&out16[idx]) = o16.u;
    }
}

// ---------------- fp32 CSR SPMM (fallback path) -----------------------------
__global__ __launch_bounds__(256) void spmm_csr(
    const int* __restrict__ rp, const int2* __restrict__ ev,
    const float* __restrict__ srcU, const float* __restrict__ srcI,
    float* __restrict__ out,
    const float* __restrict__ add1, const float* __restrict__ add2)
{
    const int gid = blockIdx.x * blockDim.x + threadIdx.x;
    const int row = gid >> 6;
    const int lane = threadIdx.x & 63;
    if (row >= NN) return;
    const int s = rp[row], e = rp[row + 1];
    float acc = 0.f;
    int i = s;
    for (; i + 3 < e; i += 4) {
        const int2 e0 = ev[i], e1 = ev[i + 1], e2 = ev[i + 2], e3 = ev[i + 3];
        const float* p0 = (e0.x < USER_N) ? (srcU + (size_t)e0.x * D)
                                          : (srcI + (size_t)(e0.x - USER_N) * D);
        const float* p1 = (e1.x < USER_N) ? (srcU + (size_t)e1.x * D)
                                          : (srcI + (size_t)(e1.x - USER_N) * D);
        const float* p2 = (e2.x < USER_N) ? (srcU + (size_t)e2.x * D)
                                          : (srcI + (size_t)(e2.x - USER_N) * D);
        const float* p3 = (e3.x < USER_N) ? (srcU + (size_t)e3.x * D)
                                          : (srcI + (size_t)(e3.x - USER_N) * D);
        acc += __int_as_float(e0.y) * p0[lane];
        acc += __int_as_float(e1.y) * p1[lane];
        acc += __int_as_float(e2.y) * p2[lane];
        acc += __int_as_float(e3.y) * p3[lane];
    }
    for (; i < e; i++) {
        const int2 e0 = ev[i];
        const float* p0 = (e0.x < USER_N) ? (srcU + (size_t)e0.x * D)
                                          : (srcI + (size_t)(e0.x - USER_N) * D);
        acc += __int_as_float(e0.y) * p0[lane];
    }
    const size_t idx = (size_t)row * D + lane;
    if (add1) acc += add1[idx];
    if (add2) acc += add2[idx];
    out[idx] = acc;
}

extern "C" void kernel_launch(void* const* d_in, const int* in_sizes, int n_in,
                              void* d_out, int out_size, void* d_ws, size_t ws_size,
                              hipStream_t stream)
{
    const int*   adj_rows = (const int*)d_in[0];
    const int*   adj_cols = (const int*)d_in[1];
    const float* adj_vals = (const float*)d_in[2];
    const int*   img_rows = (const int*)d_in[3];
    const int*   img_cols = (const int*)d_in[4];
    const float* img_vals = (const float*)d_in[5];
    const float* img_emb  = (const float*)d_in[6];
    const float* uEmb     = (const float*)d_in[7];
    const float* iEmb     = (const float*)d_in[8];
    const float* Wt       = (const float*)d_in[9];
    const float* bt       = (const float*)d_in[10];
    float* out = (float*)d_out;

    const int e_adj = in_sizes[0];
    const int e_img = in_sizes[3];
    const int e_max = e_adj > e_img ? e_adj : e_img;
    const int NB_adj = (e_adj + CHUNK - 1) / CHUNK;
    const int NB_img = (e_img + CHUNK - 1) / CHUNK;

    const size_t ndbytes = (size_t)NN * D * sizeof(float);
    const size_t nhbytes = (size_t)NN * D * sizeof(__half);

    // ---- workspace layout (aliased: recA->xC/e1p, evImg->xB, recB->x0) ----
    size_t off = 0;
    auto carve = [&](size_t bytes) { size_t p = off; off += (bytes + 255) & ~(size_t)255; return p; };
    char* base = (char*)d_ws;
    const size_t o_featsN = carve((size_t)ITEM_N * D * sizeof(float));
    const size_t o_bufA   = carve(ndbytes);
    const size_t o_bufB   = carve(ndbytes);
    const size_t o_rpAdj  = carve((NN + 1) * sizeof(int));
    const size_t o_rpImg  = carve((NN + 1) * sizeof(int));
    const size_t o_spAdj  = carve((NN + 1) * sizeof(int));
    const size_t o_bsumsA = carve(1024 * sizeof(int));
    const size_t o_bsumsB = carve(1024 * sizeof(int));
    const size_t o_histTA = carve((size_t)NBUCK * NB_adj * sizeof(int));
    const size_t o_histTB = carve((size_t)NBUCK * NB_img * sizeof(int));
    const size_t o_recA   = carve((size_t)e_max * sizeof(uint2) > nhbytes
                                      ? (size_t)e_max * sizeof(uint2) : nhbytes);
    const size_t o_evAdj  = carve((size_t)e_adj * sizeof(int2));
    const size_t need_base = off;
    const size_t o_evImg  = carve((size_t)e_img * sizeof(int2) > nhbytes
                                      ? (size_t)e_img * sizeof(int2) : nhbytes);
    const size_t o_x0     = carve((size_t)e_img * sizeof(uint2) > nhbytes
                                      ? (size_t)e_img * sizeof(uint2) : nhbytes);
    const size_t o_wt16   = carve((size_t)D * IMGD * sizeof(_Float16));
    const size_t need_h = off;

    if (ws_size < need_base) return;
    const bool use_h = (ws_size >= need_h);

    float* featsN = (float*)(base + o_featsN);
    float* bufA   = (float*)(base + o_bufA);
    float* bufB   = (float*)(base + o_bufB);
    int* rpAdj    = (int*)(base + o_rpAdj);
    int* rpImg    = (int*)(base + o_rpImg);
    int* spAdj    = (int*)(base + o_spAdj);
    int* bsumsA   = (int*)(base + o_bsumsA);
    int* bsumsB   = (int*)(base + o_bsumsB);
    int* histTA   = (int*)(base + o_histTA);
    int* histTB   = (int*)(base + o_histTB);
    uint2* recA   = (uint2*)(base + o_recA);
    uint2* recB   = (uint2*)(base + o_x0);     // dead before prep writes x0
    int2* evAdj   = (int2*)(base + o_evAdj);
    int2* evImg   = (int2*)(base + o_evImg);
    __half* xC    = (__half*)(base + o_recA);  // e1 partial, then E's out16
    __half* xB    = (__half*)(base + o_evImg);
    __half* x0    = (__half*)(base + o_x0);
    _Float16* wt16 = (_Float16*)(base + o_wt16);

    const int SPMM8_GRID = (NN + 31) / 32;
    const int SPMM_GRID = (NN * 64 + 255) / 256;
    const int RN_GRID = (ITEM_N * 64 + 255) / 256;
    const int GEMM_BLOCKS = ((ITEM_N + 31) / 32) * KSPLIT;   // 6252 = 4*1563
    const int MEGA_GRID = 1563 * 10;                          // 4:3:3 roles

    const int nA = NBUCK * NB_adj, nsbA = (nA + 1023) / 1024;
    const int nB = NBUCK * NB_img, nsbB = (nB + 1023) / 1024;
    const int CVT_BLOCKS = (NN * D / 4 + 255) / 256;
    const int WT_BLOCKS = (D * IMGD + 255) / 256;

    __half* x0I = x0 + (size_t)USER_N * D;
    __half* xBI = xB + (size_t)USER_N * D;

    // ---- merged CSR builds (recB consumed by finalize BEFORE prep runs) ----
    bucket_count2<<<NB_adj + NB_img, 256, 0, stream>>>(
        adj_rows, e_adj, NB_adj, histTA, img_rows, e_img, NB_img, histTB);
    scanA2<<<nsbA + nsbB, 1024, 0, stream>>>(
        histTA, bsumsA, nA, nsbA, histTB, bsumsB, nB);
    scanB2<<<2, 1024, 0, stream>>>(bsumsA, nsbA, bsumsB, nsbB);
    scan_apply2<<<(nA + nB + 255) / 256, 256, 0, stream>>>(
        histTA, bsumsA, nA, histTB, bsumsB, nB);
    bucket_place2<<<NB_adj + NB_img, 256, 0, stream>>>(
        adj_rows, adj_cols, adj_vals, e_adj, NB_adj, histTA, recA,
        img_rows, img_cols, img_vals, e_img, NB_img, histTB, recB);
    bucket_finalize2<<<2 * NBUCK, 1024, 0, stream>>>(
        recA, e_adj, NB_adj, histTA, rpAdj, evAdj, spAdj,
        recB, e_img, NB_img, histTB, rpImg, evImg);

    if (use_h) {
        // prep AFTER finalize (x0 aliases recB)
        prep_fused<<<CVT_BLOCKS + WT_BLOCKS, 256, 0, stream>>>(
            uEmb, iEmb, x0, xBI, Wt, wt16, CVT_BLOCKS);

        // MEGA: gemm (partials) || g -> bufA || e1U (user edges) -> xC fp16
        gemm_g<<<MEGA_GRID, 256, 0, stream>>>(
            img_emb, wt16, featsN, bufB, rpImg, evImg,
            rpAdj, spAdj, evAdj, x0, bufA, xC,
            GEMM_BLOCKS, SPMM8_GRID);

        rownorm_h4<<<RN_GRID, 256, 0, stream>>>(featsN, bufB, bt, x0I, ITEM_N);

        // e1 = e1U partial + adj item-edges @ featsN16 -> bufB + xB user fp16
        spmm_fix<<<SPMM8_GRID, 256, 0, stream>>>(
            rpAdj, spAdj, evAdj, x0, xC, bufB, xB, USER_N);

        // E = adj @ xB + e1 + g -> bufA; fp16 -> xC
        spmm_h8<<<SPMM8_GRID, 256, 0, stream>>>(
            rpAdj, evAdj, xB, bufA, xC, NN, bufB, bufA);

        // cur1 = adj @ xC -> bufB; fp16 -> x0
        spmm_h8<<<SPMM8_GRID, 256, 0, stream>>>(
            rpAdj, evAdj, xC, bufB, x0, NN, nullptr, nullptr);

        // out = adj @ x0 + E + cur1
        spmm_h8<<<SPMM8_GRID, 256, 0, stream>>>(
            rpAdj, evAdj, x0, out, nullptr, 0, bufA, bufB);
    } else {
        gemm_feats32<<<(ITEM_N + 31) / 32, 256, 0, stream>>>(img_emb, Wt, bt, featsN);
        rownorm<<<RN_GRID, 256, 0, stream>>>(featsN, ITEM_N);

        spmm_csr<<<SPMM_GRID, 256, 0, stream>>>(
            rpImg, evImg, uEmb, iEmb, bufA, nullptr, nullptr);
        spmm_csr<<<SPMM_GRID, 256, 0, stream>>>(
            rpAdj, evAdj, uEmb, featsN, bufB, nullptr, nullptr);
        spmm_csr<<<SPMM_GRID, 256, 0, stream>>>(
            rpAdj, evAdj, bufB, iEmb, bufA, bufB, bufA);
        spmm_csr<<<SPMM_GRID, 256, 0, stream>>>(
            rpAdj, evAdj, bufA, bufA + (size_t)USER_N * D, bufB, nullptr, nullptr);
        spmm_csr<<<SPMM_GRID, 256, 0, stream>>>(
            rpAdj, evAdj, bufB, bufB + (size_t)USER_N * D, out, bufA, bufB);
    }
}

// Round 21
// 559.352 us; speedup vs baseline: 1.0155x; 1.0155x over previous
//
#include <hip/hip_runtime.h>
#include <hip/hip_fp16.h>

#define USER_N 100000
#define ITEM_N 50000
#define NN (USER_N + ITEM_N)
#define D 64
#define IMGD 1024
#define LDP 68
#define KSPLIT 4
#define KQ (IMGD / KSPLIT)

#define BUCKET_BITS 10
#define BROWS (1 << BUCKET_BITS)
#define NBUCK ((NN + BROWS - 1) >> BUCKET_BITS)   // 147
#define CHUNK 4096

typedef _Float16 v4h __attribute__((ext_vector_type(4)));
typedef _Float16 v8h __attribute__((ext_vector_type(8)));
typedef float v4f __attribute__((ext_vector_type(4)));

typedef __attribute__((address_space(1))) unsigned int GU32;
typedef __attribute__((address_space(3))) unsigned int LU32;

// ------ fused prep: cvt x0=[u16;i16] (+dup i16 into xB) | wt transpose ------
__global__ __launch_bounds__(256) void prep_fused(
    const float* __restrict__ uE, const float* __restrict__ iE,
    __half* __restrict__ x0, __half* __restrict__ xBI,
    const float* __restrict__ W, _Float16* __restrict__ Wt16, int cvt_blocks)
{
    if (blockIdx.x < cvt_blocks) {
        const int i = blockIdx.x * 256 + threadIdx.x;
        const int n4u = USER_N * D / 4;
        const int n4 = NN * D / 4;
        if (i >= n4) return;
        const float4 v = (i < n4u) ? reinterpret_cast<const float4*>(uE)[i]
                                   : reinterpret_cast<const float4*>(iE)[i - n4u];
        union { uint2 u2; __half2 h[2]; } o;
        o.h[0] = __floats2half2_rn(v.x, v.y);
        o.h[1] = __floats2half2_rn(v.z, v.w);
        *reinterpret_cast<uint2*>(x0 + (size_t)i * 4) = o.u2;
        if (i >= n4u)
            *reinterpret_cast<uint2*>(xBI + (size_t)(i - n4u) * 4) = o.u2;
    } else {
        const int id = (blockIdx.x - cvt_blocks) * 256 + threadIdx.x;
        if (id >= D * IMGD) return;
        const int c = id >> 10;
        const int k = id & 1023;
        Wt16[id] = (_Float16)W[(size_t)k * D + c];
    }
}

// ---------- MEGA: gemm || spmm g, roles INTERLEAVED by blockIdx%7 -----------
__global__ __launch_bounds__(256) void gemm_g(
    const float* __restrict__ A, const _Float16* __restrict__ Wt16,
    float* __restrict__ P0, float* __restrict__ P123,
    const int* __restrict__ rp, const int2* __restrict__ ev,
    const __half* __restrict__ src, float* __restrict__ out32,
    int gemm_blocks, int g_blocks)
{
    __shared__ float As[32 * KQ];   // 32KB (gemm branch only)
    const int q = blockIdx.x / 7, r7 = blockIdx.x % 7;
    if (r7 < 4) {
        const int gb = q * 4 + r7;
        if (gb >= gemm_blocks) return;
        const int t = threadIdx.x;
        const int w = t >> 6;
        const int lane = t & 63;
        const int l16 = lane & 15;
        const int g = lane >> 4;
        const int tile = gb >> 2;
        const int ks = gb & 3;
        const int row0 = tile * 32;
        const int kbase = ks * KQ;

#pragma unroll
        for (int i = 0; i < 8; i++) {
            const int r = w * 8 + i;
            const int grow = row0 + r;
            const int garow = grow < ITEM_N ? grow : ITEM_N - 1;
            const int xm = (r & 7) << 4;
            const char* srcp = reinterpret_cast<const char*>(
                A + (size_t)garow * IMGD + kbase) + ((lane * 16) ^ xm);
            __builtin_amdgcn_global_load_lds(
                (GU32*)srcp, (LU32*)&As[r * KQ], 16, 0, 0);
        }
        asm volatile("s_waitcnt vmcnt(0)" ::: "memory");
        __syncthreads();

        const int wr = (w >> 1) * 16;
        const int wc = (w & 1) * 32;
        const int rr = wr + l16;
        const char* rbase = reinterpret_cast<const char*>(&As[rr * KQ]);
        const int xm = (rr & 7) << 4;

        v4f acc[2] = {};
        const _Float16* wb = Wt16 + (size_t)l16 * IMGD + kbase + g * 4;

        for (int c = 0; c < KQ; c += 64) {
            const int cb = c * 4;
            const float4 f0 = *reinterpret_cast<const float4*>(rbase + ((cb + g * 16) ^ xm));
            const float4 f1 = *reinterpret_cast<const float4*>(rbase + ((cb + 64 + g * 16) ^ xm));
            const float4 f2 = *reinterpret_cast<const float4*>(rbase + ((cb + 128 + g * 16) ^ xm));
            const float4 f3 = *reinterpret_cast<const float4*>(rbase + ((cb + 192 + g * 16) ^ xm));
            union { v8h v; v4h h[2]; } af0, af1;
            {
                v4h h;
                h[0] = (_Float16)f0.x; h[1] = (_Float16)f0.y;
                h[2] = (_Float16)f0.z; h[3] = (_Float16)f0.w;
                af0.h[0] = h;
                h[0] = (_Float16)f1.x; h[1] = (_Float16)f1.y;
                h[2] = (_Float16)f1.z; h[3] = (_Float16)f1.w;
                af0.h[1] = h;
                h[0] = (_Float16)f2.x; h[1] = (_Float16)f2.y;
                h[2] = (_Float16)f2.z; h[3] = (_Float16)f2.w;
                af1.h[0] = h;
                h[0] = (_Float16)f3.x; h[1] = (_Float16)f3.y;
                h[2] = (_Float16)f3.z; h[3] = (_Float16)f3.w;
                af1.h[1] = h;
            }
#pragma unroll
            for (int n = 0; n < 2; n++) {
                const _Float16* wp = wb + (size_t)(wc + n * 16) * IMGD + c;
                union { v8h v; v4h h[2]; } bf;
                bf.h[0] = *reinterpret_cast<const v4h*>(wp);
                bf.h[1] = *reinterpret_cast<const v4h*>(wp + 16);
                acc[n] = __builtin_amdgcn_mfma_f32_16x16x32_f16(af0.v, bf.v, acc[n], 0, 0, 0);
                bf.h[0] = *reinterpret_cast<const v4h*>(wp + 32);
                bf.h[1] = *reinterpret_cast<const v4h*>(wp + 48);
                acc[n] = __builtin_amdgcn_mfma_f32_16x16x32_f16(af1.v, bf.v, acc[n], 0, 0, 0);
            }
        }
        float* Cp = (ks == 0) ? P0 : P123 + (size_t)(ks - 1) * ITEM_N * D;
#pragma unroll
        for (int n = 0; n < 2; n++) {
            const int col = wc + n * 16 + l16;
#pragma unroll
            for (int r = 0; r < 4; r++) {
                const int grow = row0 + wr + g * 4 + r;
                if (grow < ITEM_N)
                    Cp[(size_t)grow * D + col] = acc[n][r];
            }
        }
    } else {
        const int sb = q * 3 + (r7 - 4);
        if (sb >= g_blocks) return;
        const int wid = (sb * 256 + threadIdx.x) >> 6;
        const int lane = threadIdx.x & 63;
        const int sub = lane >> 3;
        const int l8 = lane & 7;
        const int rowbase = wid * 8;
        if (rowbase >= NN) return;
        const int row = rowbase + sub;

        int v = 0;
        if (lane <= 8 && rowbase + lane <= NN) v = rp[rowbase + lane];
        const int s = __shfl(v, sub, 64);
        const int e = __shfl(v, sub + 1, 64);

        const __half* srcl = src + l8 * 8;
        float acc[8] = {};

        union cvt4 { uint4 u; __half2 h[4]; };
        int i = s;
        for (; i + 3 < e; i += 4) {
            const int2 E0 = ev[i], E1 = ev[i + 1], E2 = ev[i + 2], E3 = ev[i + 3];
            cvt4 g0, g1, g2, g3;
            g0.u = *reinterpret_cast<const uint4*>(srcl + (size_t)E0.x * D);
            g1.u = *reinterpret_cast<const uint4*>(srcl + (size_t)E1.x * D);
            g2.u = *reinterpret_cast<const uint4*>(srcl + (size_t)E2.x * D);
            g3.u = *reinterpret_cast<const uint4*>(srcl + (size_t)E3.x * D);
#pragma unroll
            for (int k = 0; k < 4; k++) {
                const cvt4& g = k == 0 ? g0 : k == 1 ? g1 : k == 2 ? g2 : g3;
                const float w = __int_as_float(k == 0 ? E0.y : k == 1 ? E1.y
                                               : k == 2 ? E2.y : E3.y);
#pragma unroll
                for (int j = 0; j < 4; j++) {
                    const float2 f = __half22float2(g.h[j]);
                    acc[2 * j]     += w * f.x;
                    acc[2 * j + 1] += w * f.y;
                }
            }
        }
        for (; i < e; i++) {
            const int2 E0 = ev[i];
            cvt4 g;
            g.u = *reinterpret_cast<const uint4*>(srcl + (size_t)E0.x * D);
            const float w = __int_as_float(E0.y);
#pragma unroll
            for (int j = 0; j < 4; j++) {
                const float2 f = __half22float2(g.h[j]);
                acc[2 * j]     += w * f.x;
                acc[2 * j + 1] += w * f.y;
            }
        }

        if (row >= NN) return;
        const size_t idx = (size_t)row * D + l8 * 8;
#pragma unroll
        for (int h = 0; h < 2; h++) {
            float4 o;
            o.x = acc[4 * h]; o.y = acc[4 * h + 1];
            o.z = acc[4 * h + 2]; o.w = acc[4 * h + 3];
            *reinterpret_cast<float4*>(&out32[idx + h * 4]) = o;
        }
    }
}

// ------------- fp32 GEMM (fallback path) ------------------------------------
__global__ __launch_bounds__(256) void gemm_feats32(
    const float* __restrict__ A, const float* __restrict__ W,
    const float* __restrict__ b, float* __restrict__ C)
{
    __shared__ float As[32][LDP];
    __shared__ float Ws[64][LDP];
    const int row0 = blockIdx.x * 32;
    const int t = threadIdx.x;
    const int tx = t & 15, ty = t >> 4;
    float acc[2][4] = {};

    const int lr = t >> 4;
    const int lk = (t & 15) * 4;

    for (int k0 = 0; k0 < IMGD; k0 += 64) {
#pragma unroll
        for (int i = 0; i < 2; i++) {
            const int r = lr + i * 16;
            const int grow = row0 + r;
            float4 v = make_float4(0.f, 0.f, 0.f, 0.f);
            if (grow < ITEM_N)
                v = *reinterpret_cast<const float4*>(&A[(size_t)grow * IMGD + k0 + lk]);
            *reinterpret_cast<float4*>(&As[r][lk]) = v;
        }
#pragma unroll
        for (int i = 0; i < 4; i++) {
            const int kr = lr + i * 16;
            float4 v = *reinterpret_cast<const float4*>(&W[(size_t)(k0 + kr) * D + lk]);
            *reinterpret_cast<float4*>(&Ws[kr][lk]) = v;
        }
        __syncthreads();
#pragma unroll
        for (int kb = 0; kb < 16; kb++) {
            float a_[2][4], w_[4][4];
#pragma unroll
            for (int i = 0; i < 2; i++) {
                const float4 v = *reinterpret_cast<const float4*>(&As[ty * 2 + i][kb * 4]);
                a_[i][0] = v.x; a_[i][1] = v.y; a_[i][2] = v.z; a_[i][3] = v.w;
            }
#pragma unroll
            for (int j = 0; j < 4; j++) {
                const float4 v = *reinterpret_cast<const float4*>(&Ws[kb * 4 + j][tx * 4]);
                w_[j][0] = v.x; w_[j][1] = v.y; w_[j][2] = v.z; w_[j][3] = v.w;
            }
#pragma unroll
            for (int j = 0; j < 4; j++)
#pragma unroll
                for (int i = 0; i < 2; i++)
#pragma unroll
                    for (int c = 0; c < 4; c++)
                        acc[i][c] += a_[i][j] * w_[j][c];
        }
        __syncthreads();
    }
    const float4 bias = *reinterpret_cast<const float4*>(&b[tx * 4]);
#pragma unroll
    for (int i = 0; i < 2; i++) {
        const int grow = row0 + ty * 2 + i;
        if (grow < ITEM_N) {
            float4 v;
            v.x = acc[i][0] + bias.x;
            v.y = acc[i][1] + bias.y;
            v.z = acc[i][2] + bias.z;
            v.w = acc[i][3] + bias.w;
            *reinterpret_cast<float4*>(&C[(size_t)grow * D + tx * 4]) = v;
        }
    }
}

// ---- Row L2 norm of (P0+P1+P2+P3+bias) -> fp16 (one wave per row) ----------
__global__ __launch_bounds__(256) void rownorm_h4(
    const float* __restrict__ P0, const float* __restrict__ P123,
    const float* __restrict__ b, __half* __restrict__ Y, int nrows)
{
    const int gid = blockIdx.x * blockDim.x + threadIdx.x;
    const int row = gid >> 6;
    const int lane = threadIdx.x & 63;
    if (row >= nrows) return;
    const size_t idx = (size_t)row * D + lane;
    const size_t N1 = (size_t)ITEM_N * D;
    float v = P0[idx] + P123[idx] + P123[idx + N1] + P123[idx + 2 * N1] + b[lane];
    float s = v * v;
#pragma unroll
    for (int o = 32; o > 0; o >>= 1) s += __shfl_xor(s, o, 64);
    const float scale = 1.0f / fmaxf(sqrtf(s), 1e-12f);
    Y[idx] = __float2half(v * scale);
}

__global__ __launch_bounds__(256) void rownorm(float* __restrict__ X, int nrows)
{
    const int gid = blockIdx.x * blockDim.x + threadIdx.x;
    const int row = gid >> 6;
    const int lane = threadIdx.x & 63;
    if (row >= nrows) return;
    float v = X[(size_t)row * D + lane];
    float s = v * v;
#pragma unroll
    for (int o = 32; o > 0; o >>= 1) s += __shfl_xor(s, o, 64);
    const float scale = 1.0f / fmaxf(sqrtf(s), 1e-12f);
    X[(size_t)row * D + lane] = v * scale;
}

// ============== CSR build (merged adj+img stages) ===========================
__global__ __launch_bounds__(256) void bucket_count2(
    const int* __restrict__ rows_a, int nnz_a, int nb_a, int* __restrict__ histT_a,
    const int* __restrict__ rows_b, int nnz_b, int nb_b, int* __restrict__ histT_b)
{
    const bool isA = (int)blockIdx.x < nb_a;
    const int bid = isA ? blockIdx.x : blockIdx.x - nb_a;
    const int* rows = isA ? rows_a : rows_b;
    const int nnz = isA ? nnz_a : nnz_b;
    const int nb = isA ? nb_a : nb_b;
    int* histT = isA ? histT_a : histT_b;

    __shared__ int cnt[NBUCK];
    for (int i = threadIdx.x; i < NBUCK; i += 256) cnt[i] = 0;
    __syncthreads();
    const int e0 = bid * CHUNK;
    const int e1 = min(e0 + CHUNK, nnz);
    for (int e = e0 + threadIdx.x; e < e1; e += 256)
        atomicAdd(&cnt[rows[e] >> BUCKET_BITS], 1);
    __syncthreads();
    for (int b = threadIdx.x; b < NBUCK; b += 256)
        histT[b * nb + bid] = cnt[b];
}

// merged per-block scan (adj blocks then img blocks)
__global__ __launch_bounds__(1024) void scanA2(
    int* __restrict__ histTA, int* __restrict__ bsumsA, int nA, int nsbA,
    int* __restrict__ histTB, int* __restrict__ bsumsB, int nB)
{
    const bool isA = (int)blockIdx.x < nsbA;
    int* cnt = isA ? histTA : histTB;
    int* bsums = isA ? bsumsA : bsumsB;
    const int n = isA ? nA : nB;
    const int bid = isA ? blockIdx.x : blockIdx.x - nsbA;

    const int t = threadIdx.x;
    const int gid = bid * 1024 + t;
    const int lane = t & 63, wid = t >> 6;
    int v = (gid < n) ? cnt[gid] : 0;
    int x = v;
#pragma unroll
    for (int o = 1; o < 64; o <<= 1) {
        int y = __shfl_up(x, o, 64);
        if (lane >= o) x += y;
    }
    __shared__ int ws[16];
    __shared__ int wo[16];
    if (lane == 63) ws[wid] = x;
    __syncthreads();
    if (t < 16) {
        int s = ws[t];
        int xx = s;
#pragma unroll
        for (int o = 1; o < 16; o <<= 1) {
            int y = __shfl_up(xx, o, 16);
            if (t >= o) xx += y;
        }
        wo[t] = xx - s;
        if (t == 15) bsums[bid] = xx;
    }
    __syncthreads();
    if (gid < n) cnt[gid] = x - v + wo[wid];
}

// block 0 -> bsumsA, block 1 -> bsumsB
__global__ __launch_bounds__(1024) void scanB2(
    int* __restrict__ bsA, int nbA, int* __restrict__ bsB, int nbB)
{
    int* bs = blockIdx.x == 0 ? bsA : bsB;
    const int nb = blockIdx.x == 0 ? nbA : nbB;
    const int t = threadIdx.x;
    const int lane = t & 63, wid = t >> 6;
    int v = (t < nb) ? bs[t] : 0;
    int x = v;
#pragma unroll
    for (int o = 1; o < 64; o <<= 1) {
        int y = __shfl_up(x, o, 64);
        if (lane >= o) x += y;
    }
    __shared__ int ws[16];
    __shared__ int wo[16];
    if (lane == 63) ws[wid] = x;
    __syncthreads();
    if (t < 16) {
        int s = ws[t];
        int xx = s;
#pragma unroll
        for (int o = 1; o < 16; o <<= 1) {
            int y = __shfl_up(xx, o, 16);
            if (t >= o) xx += y;
        }
        wo[t] = xx - s;
    }
    __syncthreads();
    if (t < nb) bs[t] = x - v + wo[wid];
}

__global__ __launch_bounds__(256) void scan_apply2(
    int* __restrict__ histTA, const int* __restrict__ bsA, int nA,
    int* __restrict__ histTB, const int* __restrict__ bsB, int nB)
{
    const int gid = blockIdx.x * blockDim.x + threadIdx.x;
    if (gid < nA) histTA[gid] += bsA[gid >> 10];
    else if (gid - nA < nB) histTB[gid - nA] += bsB[(gid - nA) >> 10];
}

__global__ __launch_bounds__(256) void bucket_place2(
    const int* __restrict__ rows_a, const int* __restrict__ cols_a,
    const float* __restrict__ vals_a, int nnz_a, int nb_a,
    const int* __restrict__ offsT_a, uint2* __restrict__ rec_a,
    const int* __restrict__ rows_b, const int* __restrict__ cols_b,
    const float* __restrict__ vals_b, int nnz_b, int nb_b,
    const int* __restrict__ offsT_b, uint2* __restrict__ rec_b)
{
    const bool isA = (int)blockIdx.x < nb_a;
    const int bid = isA ? blockIdx.x : blockIdx.x - nb_a;
    const int* rows = isA ? rows_a : rows_b;
    const int* cols = isA ? cols_a : cols_b;
    const float* vals = isA ? vals_a : vals_b;
    const int nnz = isA ? nnz_a : nnz_b;
    const int nb = isA ? nb_a : nb_b;
    const int* offsT = isA ? offsT_a : offsT_b;
    uint2* rec = isA ? rec_a : rec_b;

    __shared__ int cur[NBUCK];
    for (int b = threadIdx.x; b < NBUCK; b += 256)
        cur[b] = offsT[b * nb + bid];
    __syncthreads();
    const int e0 = bid * CHUNK;
    const int e1 = min(e0 + CHUNK, nnz);
    for (int e = e0 + threadIdx.x; e < e1; e += 256) {
        const int r = rows[e];
        const int b = r >> BUCKET_BITS;
        const int pos = atomicAdd(&cur[b], 1);
        rec[pos] = make_uint2(((unsigned)cols[e] << BUCKET_BITS) |
                                  (unsigned)(r & (BROWS - 1)),
                              __float_as_uint(vals[e]));
    }
}

__global__ __launch_bounds__(1024) void bucket_finalize2(
    const uint2* __restrict__ rec_a, int nnz_a, int nb_a,
    const int* __restrict__ offsT_a, int* __restrict__ rp_a, int2* __restrict__ ev_a,
    const uint2* __restrict__ rec_b, int nnz_b, int nb_b,
    const int* __restrict__ offsT_b, int* __restrict__ rp_b, int2* __restrict__ ev_b)
{
    const bool isA = (int)blockIdx.x < NBUCK;
    const int b = isA ? blockIdx.x : blockIdx.x - NBUCK;
    const uint2* rec = isA ? rec_a : rec_b;
    const int nnz = isA ? nnz_a : nnz_b;
    const int nb = isA ? nb_a : nb_b;
    const int* offsT = isA ? offsT_a : offsT_b;
    int* rp = isA ? rp_a : rp_b;
    int2* ev = isA ? ev_a : ev_b;

    const int t = threadIdx.x;
    const int rlo = b << BUCKET_BITS;
    const int segs = offsT[b * nb];
    const int sege = (b + 1 < NBUCK) ? offsT[(b + 1) * nb] : nnz;

    __shared__ int cnt[BROWS];
    __shared__ int cur[BROWS];
    cnt[t] = 0;
    __syncthreads();
    for (int i = segs + t; i < sege; i += 1024)
        atomicAdd(&cnt[rec[i].x & (BROWS - 1)], 1);
    __syncthreads();

    const int lane = t & 63, wid = t >> 6;
    const int v = cnt[t];
    int x = v;
#pragma unroll
    for (int o = 1; o < 64; o <<= 1) {
        int y = __shfl_up(x, o, 64);
        if (lane >= o) x += y;
    }
    __shared__ int wsum[16];
    __shared__ int woff[16];
    if (lane == 63) wsum[wid] = x;
    __syncthreads();
    if (t < 16) {
        int s = wsum[t];
        int xx = s;
#pragma unroll
        for (int o = 1; o < 16; o <<= 1) {
            int y = __shfl_up(xx, o, 16);
            if (t >= o) xx += y;
        }
        woff[t] = xx - s;
    }
    __syncthreads();
    const int start = segs + (x - v + woff[wid]);

    if (rlo + t < NN) rp[rlo + t] = start;
    if (b == NBUCK - 1 && t == 0) rp[NN] = nnz;
    cur[t] = start;
    __syncthreads();

    for (int i = segs + t; i < sege; i += 1024) {
        const uint2 R = rec[i];
        const int rl = (int)(R.x & (BROWS - 1));
        const int c = (int)(R.x >> BUCKET_BITS);
        const int pos = atomicAdd(&cur[rl], 1);
        ev[pos] = make_int2(c, (int)R.y);
    }
}

// ------- CSR SPMM v5: 8 rows per wave (8 lanes x 16B per row) ---------------
__global__ __launch_bounds__(256) void spmm_h8(
    const int* __restrict__ rp, const int2* __restrict__ ev,
    const __half* __restrict__ src,
    float* __restrict__ out32, __half* __restrict__ out16, int limit16,
    const float* __restrict__ add1, const float* __restrict__ add2)
{
    const int wid = (blockIdx.x * 256 + threadIdx.x) >> 6;
    const int lane = threadIdx.x & 63;
    const int sub = lane >> 3;
    const int l8 = lane & 7;
    const int rowbase = wid * 8;
    if (rowbase >= NN) return;
    const int row = rowbase + sub;

    int v = 0;
    if (lane <= 8 && rowbase + lane <= NN) v = rp[rowbase + lane];
    const int s = __shfl(v, sub, 64);
    const int e = __shfl(v, sub + 1, 64);

    const __half* srcl = src + l8 * 8;
    float acc[8] = {};

    union cvt4 { uint4 u; __half2 h[4]; };
    int i = s;
    for (; i + 3 < e; i += 4) {
        const int2 E0 = ev[i], E1 = ev[i + 1], E2 = ev[i + 2], E3 = ev[i + 3];
        cvt4 g0, g1, g2, g3;
        g0.u = *reinterpret_cast<const uint4*>(srcl + (size_t)E0.x * D);
        g1.u = *reinterpret_cast<const uint4*>(srcl + (size_t)E1.x * D);
        g2.u = *reinterpret_cast<const uint4*>(srcl + (size_t)E2.x * D);
        g3.u = *reinterpret_cast<const uint4*>(srcl + (size_t)E3.x * D);
#pragma unroll
        for (int k = 0; k < 4; k++) {
            const cvt4& g = k == 0 ? g0 : k == 1 ? g1 : k == 2 ? g2 : g3;
            const float w = __int_as_float(k == 0 ? E0.y : k == 1 ? E1.y
                                           : k == 2 ? E2.y : E3.y);
#pragma unroll
            for (int j = 0; j < 4; j++) {
                const float2 f = __half22float2(g.h[j]);
                acc[2 * j]     += w * f.x;
                acc[2 * j + 1] += w * f.y;
            }
        }
    }
    for (; i < e; i++) {
        const int2 E0 = ev[i];
        cvt4 g;
        g.u = *reinterpret_cast<const uint4*>(srcl + (size_t)E0.x * D);
        const float w = __int_as_float(E0.y);
#pragma unroll
        for (int j = 0; j < 4; j++) {
            const float2 f = __half22float2(g.h[j]);
            acc[2 * j]     += w * f.x;
            acc[2 * j + 1] += w * f.y;
        }
    }

    if (row >= NN) return;
    const size_t idx = (size_t)row * D + l8 * 8;
#pragma unroll
    for (int h = 0; h < 2; h++) {
        if (add1) {
            const float4 a = *reinterpret_cast<const float4*>(&add1[idx + h * 4]);
            acc[4 * h] += a.x; acc[4 * h + 1] += a.y;
            acc[4 * h + 2] += a.z; acc[4 * h + 3] += a.w;
        }
        if (add2) {
            const float4 a = *reinterpret_cast<const float4*>(&add2[idx + h * 4]);
            acc[4 * h] += a.x; acc[4 * h + 1] += a.y;
            acc[4 * h + 2] += a.z; acc[4 * h + 3] += a.w;
        }
        float4 o;
        o.x = acc[4 * h]; o.y = acc[4 * h + 1];
        o.z = acc[4 * h + 2]; o.w = acc[4 * h + 3];
        *reinterpret_cast<float4*>(&out32[idx + h * 4]) = o;
    }
    if (row < limit16) {
        cvt4 o16;
#pragma unroll
        for (int j = 0; j < 4; j++)
            o16.h[j] = __floats2half2_rn(acc[2 * j], acc[2 * j + 1]);
        *reinterpret_cast<uint4*>(&out16[idx]) = o16.u;
    }
}

// ---------------- fp32 CSR SPMM (fallback path) -----------------------------
__global__ __launch_bounds__(256) void spmm_csr(
    const int* __restrict__ rp, const int2* __restrict__ ev,
    const float* __restrict__ srcU, const float* __restrict__ srcI,
    float* __restrict__ out,
    const float* __restrict__ add1, const float* __restrict__ add2)
{
    const int gid = blockIdx.x * blockDim.x + threadIdx.x;
    const int row = gid >> 6;
    const int lane = threadIdx.x & 63;
    if (row >= NN) return;
    const int s = rp[row], e = rp[row + 1];
    float acc = 0.f;
    int i = s;
    for (; i + 3 < e; i += 4) {
        const int2 e0 = ev[i], e1 = ev[i + 1], e2 = ev[i + 2], e3 = ev[i + 3];
        const float* p0 = (e0.x < USER_N) ? (srcU + (size_t)e0.x * D)
                                          : (srcI + (size_t)(e0.x - USER_N) * D);
        const float* p1 = (e1.x < USER_N) ? (srcU + (size_t)e1.x * D)
                                          : (srcI + (size_t)(e1.x - USER_N) * D);
        const float* p2 = (e2.x < USER_N) ? (srcU + (size_t)e2.x * D)
                                          : (srcI + (size_t)(e2.x - USER_N) * D);
        const float* p3 = (e3.x < USER_N) ? (srcU + (size_t)e3.x * D)
                                          : (srcI + (size_t)(e3.x - USER_N) * D);
        acc += __int_as_float(e0.y) * p0[lane];
        acc += __int_as_float(e1.y) * p1[lane];
        acc += __int_as_float(e2.y) * p2[lane];
        acc += __int_as_float(e3.y) * p3[lane];
    }
    for (; i < e; i++) {
        const int2 e0 = ev[i];
        const float* p0 = (e0.x < USER_N) ? (srcU + (size_t)e0.x * D)
                                          : (srcI + (size_t)(e0.x - USER_N) * D);
        acc += __int_as_float(e0.y) * p0[lane];
    }
    const size_t idx = (size_t)row * D + lane;
    if (add1) acc += add1[idx];
    if (add2) acc += add2[idx];
    out[idx] = acc;
}

extern "C" void kernel_launch(void* const* d_in, const int* in_sizes, int n_in,
                              void* d_out, int out_size, void* d_ws, size_t ws_size,
                              hipStream_t stream)
{
    const int*   adj_rows = (const int*)d_in[0];
    const int*   adj_cols = (const int*)d_in[1];
    const float* adj_vals = (const float*)d_in[2];
    const int*   img_rows = (const int*)d_in[3];
    const int*   img_cols = (const int*)d_in[4];
    const float* img_vals = (const float*)d_in[5];
    const float* img_emb  = (const float*)d_in[6];
    const float* uEmb     = (const float*)d_in[7];
    const float* iEmb     = (const float*)d_in[8];
    const float* Wt       = (const float*)d_in[9];
    const float* bt       = (const float*)d_in[10];
    float* out = (float*)d_out;

    const int e_adj = in_sizes[0];
    const int e_img = in_sizes[3];
    const int e_max = e_adj > e_img ? e_adj : e_img;
    const int NB_adj = (e_adj + CHUNK - 1) / CHUNK;
    const int NB_img = (e_img + CHUNK - 1) / CHUNK;

    const size_t ndbytes = (size_t)NN * D * sizeof(float);
    const size_t nhbytes = (size_t)NN * D * sizeof(__half);

    // ---- workspace layout (aliased: recA->xC, evImg->xB, recB->x0 carve) ----
    size_t off = 0;
    auto carve = [&](size_t bytes) { size_t p = off; off += (bytes + 255) & ~(size_t)255; return p; };
    char* base = (char*)d_ws;
    const size_t o_featsN = carve((size_t)ITEM_N * D * sizeof(float));
    const size_t o_bufA   = carve(ndbytes);
    const size_t o_bufB   = carve(ndbytes);
    const size_t o_rpAdj  = carve((NN + 1) * sizeof(int));
    const size_t o_rpImg  = carve((NN + 1) * sizeof(int));
    const size_t o_bsumsA = carve(1024 * sizeof(int));
    const size_t o_bsumsB = carve(1024 * sizeof(int));
    const size_t o_histTA = carve((size_t)NBUCK * NB_adj * sizeof(int));
    const size_t o_histTB = carve((size_t)NBUCK * NB_img * sizeof(int));
    const size_t o_recA   = carve((size_t)e_max * sizeof(uint2) > nhbytes
                                      ? (size_t)e_max * sizeof(uint2) : nhbytes);
    const size_t o_evAdj  = carve((size_t)e_adj * sizeof(int2));
    const size_t need_base = off;
    const size_t o_evImg  = carve((size_t)e_img * sizeof(int2) > nhbytes
                                      ? (size_t)e_img * sizeof(int2) : nhbytes);
    const size_t o_x0     = carve((size_t)e_img * sizeof(uint2) > nhbytes
                                      ? (size_t)e_img * sizeof(uint2) : nhbytes);
    const size_t o_wt16   = carve((size_t)D * IMGD * sizeof(_Float16));
    const size_t need_h = off;

    if (ws_size < need_base) return;
    const bool use_h = (ws_size >= need_h);

    float* featsN = (float*)(base + o_featsN);
    float* bufA   = (float*)(base + o_bufA);
    float* bufB   = (float*)(base + o_bufB);
    int* rpAdj    = (int*)(base + o_rpAdj);
    int* rpImg    = (int*)(base + o_rpImg);
    int* bsumsA   = (int*)(base + o_bsumsA);
    int* bsumsB   = (int*)(base + o_bsumsB);
    int* histTA   = (int*)(base + o_histTA);
    int* histTB   = (int*)(base + o_histTB);
    uint2* recA   = (uint2*)(base + o_recA);
    uint2* recB   = (uint2*)(base + o_x0);
    int2* evAdj   = (int2*)(base + o_evAdj);
    int2* evImg   = (int2*)(base + o_evImg);
    __half* xC    = (__half*)(base + o_recA);
    __half* xB    = (__half*)(base + o_evImg);
    __half* x0    = (__half*)(base + o_x0);
    _Float16* wt16 = (_Float16*)(base + o_wt16);

    const int SPMM8_GRID = (NN + 31) / 32;
    const int SPMM_GRID = (NN * 64 + 255) / 256;
    const int RN_GRID = (ITEM_N * 64 + 255) / 256;
    const int GEMM_BLOCKS = ((ITEM_N + 31) / 32) * KSPLIT;   // 6252 = 4*1563
    const int MEGA_GRID = 1563 * 7;                           // 4:3 interleave

    // ---- merged CSR builds ----
    const int nA = NBUCK * NB_adj, nsbA = (nA + 1023) / 1024;
    const int nB = NBUCK * NB_img, nsbB = (nB + 1023) / 1024;
    bucket_count2<<<NB_adj + NB_img, 256, 0, stream>>>(
        adj_rows, e_adj, NB_adj, histTA, img_rows, e_img, NB_img, histTB);
    scanA2<<<nsbA + nsbB, 1024, 0, stream>>>(
        histTA, bsumsA, nA, nsbA, histTB, bsumsB, nB);
    scanB2<<<2, 1024, 0, stream>>>(bsumsA, nsbA, bsumsB, nsbB);
    scan_apply2<<<(nA + nB + 255) / 256, 256, 0, stream>>>(
        histTA, bsumsA, nA, histTB, bsumsB, nB);
    bucket_place2<<<NB_adj + NB_img, 256, 0, stream>>>(
        adj_rows, adj_cols, adj_vals, e_adj, NB_adj, histTA, recA,
        img_rows, img_cols, img_vals, e_img, NB_img, histTB, recB);
    bucket_finalize2<<<2 * NBUCK, 1024, 0, stream>>>(
        recA, e_adj, NB_adj, histTA, rpAdj, evAdj,
        recB, e_img, NB_img, histTB, rpImg, evImg);

    if (use_h) {
        __half* x0I = x0 + (size_t)USER_N * D;
        __half* xBI = xB + (size_t)USER_N * D;

        const int CVT_BLOCKS = (NN * D / 4 + 255) / 256;
        prep_fused<<<CVT_BLOCKS + (D * IMGD + 255) / 256, 256, 0, stream>>>(
            uEmb, iEmb, x0, xBI, Wt, wt16, CVT_BLOCKS);

        // MEGA: gemm (partials -> featsN+bufB) || g = img_adj@x0 -> bufA
        gemm_g<<<MEGA_GRID, 256, 0, stream>>>(
            img_emb, wt16, featsN, bufB, rpImg, evImg, x0, bufA,
            GEMM_BLOCKS, SPMM8_GRID);

        rownorm_h4<<<RN_GRID, 256, 0, stream>>>(featsN, bufB, bt, x0I, ITEM_N);

        // e1 = adj @ x0 -> bufB; fp16 user rows -> xB  (xB = [e1_U; i16])
        spmm_h8<<<SPMM8_GRID, 256, 0, stream>>>(
            rpAdj, evAdj, x0, bufB, xB, USER_N, nullptr, nullptr);

        // E = adj @ xB + e1 + g -> bufA; fp16 -> xC
        spmm_h8<<<SPMM8_GRID, 256, 0, stream>>>(
            rpAdj, evAdj, xB, bufA, xC, NN, bufB, bufA);

        // cur1 = adj @ xC -> bufB; fp16 -> x0
        spmm_h8<<<SPMM8_GRID, 256, 0, stream>>>(
            rpAdj, evAdj, xC, bufB, x0, NN, nullptr, nullptr);

        // out = adj @ x0 + E + cur1
        spmm_h8<<<SPMM8_GRID, 256, 0, stream>>>(
            rpAdj, evAdj, x0, out, nullptr, 0, bufA, bufB);
    } else {
        gemm_feats32<<<(ITEM_N + 31) / 32, 256, 0, stream>>>(img_emb, Wt, bt, featsN);
        rownorm<<<RN_GRID, 256, 0, stream>>>(featsN, ITEM_N);

        spmm_csr<<<SPMM_GRID, 256, 0, stream>>>(
            rpImg, evImg, uEmb, iEmb, bufA, nullptr, nullptr);
        spmm_csr<<<SPMM_GRID, 256, 0, stream>>>(
            rpAdj, evAdj, uEmb, featsN, bufB, nullptr, nullptr);
        spmm_csr<<<SPMM_GRID, 256, 0, stream>>>(
            rpAdj, evAdj, bufB, iEmb, bufA, bufB, bufA);
        spmm_csr<<<SPMM_GRID, 256, 0, stream>>>(
            rpAdj, evAdj, bufA, bufA + (size_t)USER_N * D, bufB, nullptr, nullptr);
        spmm_csr<<<SPMM_GRID, 256, 0, stream>>>(
            rpAdj, evAdj, bufB, bufB + (size_t)USER_N * D, out, bufA, bufB);
    }
}